// Round 4
// baseline (335.410 us; speedup 1.0000x reference)
//
#include <hip/hip_runtime.h>
#include <hip/hip_bf16.h>
#include <math.h>

typedef __attribute__((ext_vector_type(8))) short bf16x8;
typedef __attribute__((ext_vector_type(4))) float f32x4;
typedef __attribute__((ext_vector_type(4))) unsigned short u16x4;

#define TOKENS 8192
#define EMB 256
#define SEQ 4096
#define NH 8
#define HD 32
#define FFN_DIM 1024

__device__ __forceinline__ unsigned short f2bf_bits(float f) {
  unsigned u = __builtin_bit_cast(unsigned, f);
  u += 0x7FFFu + ((u >> 16) & 1u);
  return (unsigned short)(u >> 16);
}

// ---------------- weight convert + transpose: WT[n][k] = bf16(W[k][n]) ----------------
__global__ __launch_bounds__(256) void wtrans_kernel(const float* __restrict__ w,
                                                     unsigned short* __restrict__ wt,
                                                     int K, int N) {
  int id = blockIdx.x * 256 + threadIdx.x;
  if (id >= N * K) return;
  int n = id / K, kk = id - n * K;
  wt[id] = f2bf_bits(w[(size_t)kk * N + n]);
}

// ---------------- layernorm: fp32 in -> bf16 out (one wave per token) ----------------
__global__ __launch_bounds__(256) void ln_kernel(const float* __restrict__ x,
                                                 const float* __restrict__ g,
                                                 const float* __restrict__ b,
                                                 unsigned short* __restrict__ out) {
  const int tid = threadIdx.x, lane = tid & 63, wid = tid >> 6;
  const int token = blockIdx.x * 4 + wid;
  const float4 v = *(const float4*)(x + (size_t)token * EMB + lane * 4);
  float s = v.x + v.y + v.z + v.w;
#pragma unroll
  for (int m = 1; m < 64; m <<= 1) s += __shfl_xor(s, m);
  const float mean = s * (1.f / 256.f);
  const float dx = v.x - mean, dy = v.y - mean, dz = v.z - mean, dw = v.w - mean;
  float qv = dx * dx + dy * dy + dz * dz + dw * dw;
#pragma unroll
  for (int m = 1; m < 64; m <<= 1) qv += __shfl_xor(qv, m);
  const float rinv = rsqrtf(qv * (1.f / 256.f) + 1e-5f);
  const float4 gg = *(const float4*)(g + lane * 4);
  const float4 bb = *(const float4*)(b + lane * 4);
  u16x4 ov;
  ov[0] = f2bf_bits(dx * rinv * gg.x + bb.x);
  ov[1] = f2bf_bits(dy * rinv * gg.y + bb.y);
  ov[2] = f2bf_bits(dz * rinv * gg.z + bb.z);
  ov[3] = f2bf_bits(dw * rinv * gg.w + bb.w);
  *(u16x4*)(out + (size_t)token * EMB + lane * 4) = ov;
}

// ---------------- GEMM: C[M,N] = A[M,K](bf16) * WT[N,K]^T (bf16), fused epilogues -----
// MODE 0: qkv scatter -> q[bh][s][d], k[bh][s][d], vT[bh][d][s] (bf16)
// MODE 1: + bias + resid(f32) -> f32 out
// MODE 2: + bias + exact GELU -> bf16 out
// MODE 3: + bias + resid(f32) -> f32 out (same as 1)
template <int MODE>
__global__ __launch_bounds__(256) void gemm_kernel(
    const unsigned short* __restrict__ A, const unsigned short* __restrict__ WT,
    const float* __restrict__ bias, const float* __restrict__ resid,
    void* __restrict__ out0, void* __restrict__ out1, void* __restrict__ out2,
    int K, int N) {
  __shared__ __align__(16) short ldsA[128 * 64];
  __shared__ __align__(16) short ldsB[128 * 64];
  const int tid = threadIdx.x;
  const int lane = tid & 63, wid = tid >> 6;
  const int llo = lane & 15, lhi = lane >> 4;
  const int m0 = blockIdx.x * 128;
  const int n0 = blockIdx.y * 128;
  const int wm = (wid >> 1) * 64, wn = (wid & 1) * 64;

  f32x4 zero4 = {0.f, 0.f, 0.f, 0.f};
  f32x4 acc[4][4];
#pragma unroll
  for (int i = 0; i < 4; ++i)
#pragma unroll
    for (int j = 0; j < 4; ++j) acc[i][j] = zero4;

  const int nkb = K >> 6;
  for (int kb = 0; kb < nkb; ++kb) {
#pragma unroll
    for (int p = 0; p < 4; ++p) {
      int idx = p * 256 + tid;
      int r = idx >> 3, ch = idx & 7;
      bf16x8 va = *(const bf16x8*)(A + (size_t)(m0 + r) * K + kb * 64 + ch * 8);
      *(bf16x8*)&ldsA[r * 64 + ((ch ^ (r & 7)) * 8)] = va;
      bf16x8 vb = *(const bf16x8*)(WT + (size_t)(n0 + r) * K + kb * 64 + ch * 8);
      *(bf16x8*)&ldsB[r * 64 + ((ch ^ (r & 7)) * 8)] = vb;
    }
    __syncthreads();
#pragma unroll
    for (int ks = 0; ks < 2; ++ks) {
      bf16x8 af[4], bfr[4];
#pragma unroll
      for (int mf = 0; mf < 4; ++mf) {
        int r = wm + mf * 16 + llo;
        af[mf] = *(const bf16x8*)&ldsA[r * 64 + (((ks * 4 + lhi) ^ (r & 7)) * 8)];
      }
#pragma unroll
      for (int nf = 0; nf < 4; ++nf) {
        int r = wn + nf * 16 + llo;
        bfr[nf] = *(const bf16x8*)&ldsB[r * 64 + (((ks * 4 + lhi) ^ (r & 7)) * 8)];
      }
#pragma unroll
      for (int mf = 0; mf < 4; ++mf)
#pragma unroll
        for (int nf = 0; nf < 4; ++nf)
          acc[mf][nf] = __builtin_amdgcn_mfma_f32_16x16x32_bf16(af[mf], bfr[nf], acc[mf][nf], 0, 0, 0);
    }
    __syncthreads();
  }

#pragma unroll
  for (int mf = 0; mf < 4; ++mf) {
#pragma unroll
    for (int nf = 0; nf < 4; ++nf) {
      const int n = n0 + wn + nf * 16 + llo;
      const float bv = bias[n];
#pragma unroll
      for (int r = 0; r < 4; ++r) {
        const int m = m0 + wm + mf * 16 + lhi * 4 + r;
        float val = acc[mf][nf][r] + bv;
        if constexpr (MODE == 0) {
          const int part = n >> 8, rem = n & 255, h = rem >> 5, d = rem & 31;
          const int bb = m >> 12, s = m & 4095, bh = bb * 8 + h;
          unsigned short ob = f2bf_bits(val);
          if (part == 0)
            ((unsigned short*)out0)[((size_t)bh * SEQ + s) * HD + d] = ob;
          else if (part == 1)
            ((unsigned short*)out1)[((size_t)bh * SEQ + s) * HD + d] = ob;
          else
            ((unsigned short*)out2)[((size_t)bh * HD + d) * SEQ + s] = ob;
        } else if constexpr (MODE == 2) {
          float gel = 0.5f * val * (1.0f + erff(val * 0.70710678118654752f));
          ((unsigned short*)out0)[(size_t)m * N + n] = f2bf_bits(gel);
        } else {
          ((float*)out0)[(size_t)m * N + n] = val + resid[(size_t)m * N + n];
        }
      }
    }
  }
}

// ---------------- flash attention: 4 waves x 32 q-rows, 64-key tiles ----------------
// NOTE: plds is WAVE-PRIVATE (each wave reads/writes only plds[wid]); LDS ops
// within a wave complete in order, so NO block barrier is needed in the main
// loop. Removing __syncthreads avoids the implicit vmcnt(0) drain that would
// kill the K/V register prefetch (m97 barrier-drain mechanism).
__global__ __launch_bounds__(256) void attn_kernel(const unsigned short* __restrict__ q,
                                                   const unsigned short* __restrict__ k,
                                                   const unsigned short* __restrict__ vT,
                                                   unsigned short* __restrict__ o) {
  __shared__ __align__(16) short plds[4][32 * 64];
  const int tid = threadIdx.x, lane = tid & 63, wid = tid >> 6;
  const int llo = lane & 15, lhi = lane >> 4;
  const int bh = blockIdx.y, qb = blockIdx.x;
  const int bb = bh >> 3, hh = bh & 7;
  const int q0 = qb * 128 + wid * 32;
  const unsigned short* qp = q + (size_t)bh * SEQ * HD;
  const unsigned short* kp = k + (size_t)bh * SEQ * HD;
  const unsigned short* vp = vT + (size_t)bh * HD * SEQ;

  f32x4 zero4 = {0.f, 0.f, 0.f, 0.f};
  bf16x8 qf[2];
#pragma unroll
  for (int mf = 0; mf < 2; ++mf)
    qf[mf] = *(const bf16x8*)(qp + (size_t)(q0 + mf * 16 + llo) * HD + lhi * 8);

  f32x4 acc[2][2];
  float mrun[2][4], lrun[2][4];
#pragma unroll
  for (int mf = 0; mf < 2; ++mf) {
    acc[mf][0] = zero4;
    acc[mf][1] = zero4;
#pragma unroll
    for (int r = 0; r < 4; ++r) { mrun[mf][r] = -1e30f; lrun[mf][r] = 0.f; }
  }

  bf16x8 kf0[4], vf0[4], kf1[4], vf1[4];

  auto load_k = [&](int tt, bf16x8(&kf)[4]) {
#pragma unroll
    for (int tf = 0; tf < 4; ++tf)
      kf[tf] = *(const bf16x8*)(kp + (size_t)(tt * 64 + tf * 16 + llo) * HD + lhi * 8);
  };
  auto load_v = [&](int tt, bf16x8(&vf)[4]) {
#pragma unroll
    for (int df = 0; df < 2; ++df)
#pragma unroll
      for (int ks = 0; ks < 2; ++ks)
        vf[df * 2 + ks] =
            *(const bf16x8*)(vp + (size_t)(df * 16 + llo) * SEQ + tt * 64 + ks * 32 + lhi * 8);
  };

  const float scale = 0.17677669529663687f;

  auto step = [&](int tt, bf16x8(&kf)[4], bf16x8(&vf)[4], bf16x8(&kn)[4], bf16x8(&vn)[4]) {
    int tn = tt + 1;
    if (tn > 63) tn = 63;
    load_k(tn, kn);
    load_v(tn, vn);
    f32x4 sc[2][4];
#pragma unroll
    for (int mf = 0; mf < 2; ++mf)
#pragma unroll
      for (int tf = 0; tf < 4; ++tf)
        sc[mf][tf] = __builtin_amdgcn_mfma_f32_16x16x32_bf16(qf[mf], kf[tf], zero4, 0, 0, 0);
#pragma unroll
    for (int mf = 0; mf < 2; ++mf) {
#pragma unroll
      for (int r = 0; r < 4; ++r) {
        float rm = fmaxf(fmaxf(sc[mf][0][r], sc[mf][1][r]), fmaxf(sc[mf][2][r], sc[mf][3][r]));
        rm = fmaxf(rm, __shfl_xor(rm, 1));
        rm = fmaxf(rm, __shfl_xor(rm, 2));
        rm = fmaxf(rm, __shfl_xor(rm, 4));
        rm = fmaxf(rm, __shfl_xor(rm, 8));
        rm *= scale;
        const float mn = fmaxf(mrun[mf][r], rm);
        const float al = __expf(mrun[mf][r] - mn);
        mrun[mf][r] = mn;
        float rs = 0.f;
#pragma unroll
        for (int tf = 0; tf < 4; ++tf) {
          float p = __expf(__builtin_fmaf(sc[mf][tf][r], scale, -mn));
          sc[mf][tf][r] = p;
          rs += p;
        }
        rs += __shfl_xor(rs, 1);
        rs += __shfl_xor(rs, 2);
        rs += __shfl_xor(rs, 4);
        rs += __shfl_xor(rs, 8);
        lrun[mf][r] = lrun[mf][r] * al + rs;
        acc[mf][0][r] *= al;
        acc[mf][1][r] *= al;
      }
    }
#pragma unroll
    for (int mf = 0; mf < 2; ++mf)
#pragma unroll
      for (int tf = 0; tf < 4; ++tf)
#pragma unroll
        for (int r = 0; r < 4; ++r) {
          const int row = mf * 16 + lhi * 4 + r;
          const int col = tf * 16 + llo;
          const int sch = (col >> 3) ^ (row & 7);
          plds[wid][row * 64 + sch * 8 + (col & 7)] = (short)f2bf_bits(sc[mf][tf][r]);
        }
    // no __syncthreads(): plds[wid] is wave-private; in-wave LDS ordering suffices
#pragma unroll
    for (int ks = 0; ks < 2; ++ks) {
      bf16x8 pa[2];
#pragma unroll
      for (int mf = 0; mf < 2; ++mf) {
        const int row = mf * 16 + llo;
        const int sch = (ks * 4 + lhi) ^ (row & 7);
        pa[mf] = *(const bf16x8*)&plds[wid][row * 64 + sch * 8];
      }
#pragma unroll
      for (int mf = 0; mf < 2; ++mf)
#pragma unroll
        for (int df = 0; df < 2; ++df)
          acc[mf][df] =
              __builtin_amdgcn_mfma_f32_16x16x32_bf16(pa[mf], vf[df * 2 + ks], acc[mf][df], 0, 0, 0);
    }
  };

  load_k(0, kf0);
  load_v(0, vf0);
  for (int t2 = 0; t2 < 32; ++t2) {
    step(t2 * 2, kf0, vf0, kf1, vf1);
    step(t2 * 2 + 1, kf1, vf1, kf0, vf0);
  }

#pragma unroll
  for (int mf = 0; mf < 2; ++mf)
#pragma unroll
    for (int df = 0; df < 2; ++df)
#pragma unroll
      for (int r = 0; r < 4; ++r) {
        const int mrow = q0 + mf * 16 + lhi * 4 + r;
        const float val = acc[mf][df][r] / lrun[mf][r];
        o[(size_t)(bb * SEQ + mrow) * EMB + hh * 32 + df * 16 + llo] = f2bf_bits(val);
      }
}

extern "C" void kernel_launch(void* const* d_in, const int* in_sizes, int n_in,
                              void* d_out, int out_size, void* d_ws, size_t ws_size,
                              hipStream_t stream) {
  const float* x = (const float*)d_in[0];
  const float* ln1_g = (const float*)d_in[1];
  const float* ln1_b = (const float*)d_in[2];
  const float* ln2_g = (const float*)d_in[3];
  const float* ln2_b = (const float*)d_in[4];
  const float* w_qkv = (const float*)d_in[5];
  const float* b_qkv = (const float*)d_in[6];
  const float* w_out = (const float*)d_in[7];
  const float* b_out = (const float*)d_in[8];
  const float* w_fc1 = (const float*)d_in[9];
  const float* b_fc1 = (const float*)d_in[10];
  const float* w_fc2 = (const float*)d_in[11];
  const float* b_fc2 = (const float*)d_in[12];
  float* out = (float*)d_out;

  char* ws = (char*)d_ws;
  size_t off = 0;
  auto alloc = [&](size_t bytes) {
    void* p = ws + off;
    off += (bytes + 255) & ~(size_t)255;
    return p;
  };
  unsigned short* wqkvT = (unsigned short*)alloc((size_t)768 * 256 * 2);
  unsigned short* woutT = (unsigned short*)alloc((size_t)256 * 256 * 2);
  unsigned short* wfc1T = (unsigned short*)alloc((size_t)1024 * 256 * 2);
  unsigned short* wfc2T = (unsigned short*)alloc((size_t)256 * 1024 * 2);
  unsigned short* ln1o = (unsigned short*)alloc((size_t)TOKENS * EMB * 2);
  unsigned short* qbuf = (unsigned short*)alloc((size_t)16 * SEQ * HD * 2);
  unsigned short* kbuf = (unsigned short*)alloc((size_t)16 * SEQ * HD * 2);
  unsigned short* vTbuf = (unsigned short*)alloc((size_t)16 * SEQ * HD * 2);
  unsigned short* obuf = (unsigned short*)alloc((size_t)TOKENS * EMB * 2);
  float* x1 = (float*)alloc((size_t)TOKENS * EMB * 4);
  unsigned short* h2 = (unsigned short*)alloc((size_t)TOKENS * EMB * 2);
  unsigned short* ffn1 = (unsigned short*)alloc((size_t)TOKENS * FFN_DIM * 2);

  dim3 blk(256);
  wtrans_kernel<<<dim3((768 * 256 + 255) / 256), blk, 0, stream>>>(w_qkv, wqkvT, 256, 768);
  wtrans_kernel<<<dim3((256 * 256 + 255) / 256), blk, 0, stream>>>(w_out, woutT, 256, 256);
  wtrans_kernel<<<dim3((1024 * 256 + 255) / 256), blk, 0, stream>>>(w_fc1, wfc1T, 256, 1024);
  wtrans_kernel<<<dim3((256 * 1024 + 255) / 256), blk, 0, stream>>>(w_fc2, wfc2T, 1024, 256);

  ln_kernel<<<dim3(TOKENS / 4), blk, 0, stream>>>(x, ln1_g, ln1_b, ln1o);

  gemm_kernel<0><<<dim3(64, 6), blk, 0, stream>>>(ln1o, wqkvT, b_qkv, nullptr,
                                                  qbuf, kbuf, vTbuf, 256, 768);

  attn_kernel<<<dim3(32, 16), blk, 0, stream>>>(qbuf, kbuf, vTbuf, obuf);

  gemm_kernel<1><<<dim3(64, 2), blk, 0, stream>>>(obuf, woutT, b_out, x,
                                                  x1, nullptr, nullptr, 256, 256);

  ln_kernel<<<dim3(TOKENS / 4), blk, 0, stream>>>(x1, ln2_g, ln2_b, h2);

  gemm_kernel<2><<<dim3(64, 8), blk, 0, stream>>>(h2, wfc1T, b_fc1, nullptr,
                                                  ffn1, nullptr, nullptr, 256, 1024);

  gemm_kernel<3><<<dim3(64, 2), blk, 0, stream>>>(ffn1, wfc2T, b_fc2, x1,
                                                  out, nullptr, nullptr, 1024, 256);
}

// Round 7
// 319.468 us; speedup vs baseline: 1.0499x; 1.0499x over previous
//
#include <hip/hip_runtime.h>
#include <hip/hip_bf16.h>
#include <math.h>

typedef __attribute__((ext_vector_type(8))) short bf16x8;
typedef __attribute__((ext_vector_type(4))) float f32x4;
typedef __attribute__((ext_vector_type(4))) unsigned short u16x4;

#define TOKENS 8192
#define EMB 256
#define SEQ 4096
#define NH 8
#define HD 32
#define FFN_DIM 1024

__device__ __forceinline__ unsigned short f2bf_bits(float f) {
  unsigned u = __builtin_bit_cast(unsigned, f);
  u += 0x7FFFu + ((u >> 16) & 1u);
  return (unsigned short)(u >> 16);
}

// ---------------- all-weights convert + transpose (one launch) ----------------
// segments: qkv [256,768], out [256,256], fc1 [256,1024], fc2 [1024,256]
__global__ __launch_bounds__(256) void wtrans_all_kernel(
    const float* __restrict__ w_qkv, const float* __restrict__ w_out,
    const float* __restrict__ w_fc1, const float* __restrict__ w_fc2,
    unsigned short* __restrict__ t_qkv, unsigned short* __restrict__ t_out,
    unsigned short* __restrict__ t_fc1, unsigned short* __restrict__ t_fc2) {
  int id = blockIdx.x * 256 + threadIdx.x;
  const int S0 = 256 * 768, S1 = S0 + 256 * 256, S2 = S1 + 256 * 1024, S3 = S2 + 1024 * 256;
  if (id < S0) {
    int n = id / 256, kk = id - n * 256;  // K=256, N=768
    t_qkv[id] = f2bf_bits(w_qkv[(size_t)kk * 768 + n]);
  } else if (id < S1) {
    int r = id - S0; int n = r / 256, kk = r - n * 256;  // K=256, N=256
    t_out[r] = f2bf_bits(w_out[(size_t)kk * 256 + n]);
  } else if (id < S2) {
    int r = id - S1; int n = r / 256, kk = r - n * 256;  // K=256, N=1024
    t_fc1[r] = f2bf_bits(w_fc1[(size_t)kk * 1024 + n]);
  } else if (id < S3) {
    int r = id - S2; int n = r / 1024, kk = r - n * 1024;  // K=1024, N=256
    t_fc2[r] = f2bf_bits(w_fc2[(size_t)kk * 256 + n]);
  }
}

// ---------------- layernorm: fp32 in -> bf16 out (one wave per token) ----------------
__global__ __launch_bounds__(256) void ln_kernel(const float* __restrict__ x,
                                                 const float* __restrict__ g,
                                                 const float* __restrict__ b,
                                                 unsigned short* __restrict__ out) {
  const int tid = threadIdx.x, lane = tid & 63, wid = tid >> 6;
  const int token = blockIdx.x * 4 + wid;
  const float4 v = *(const float4*)(x + (size_t)token * EMB + lane * 4);
  float s = v.x + v.y + v.z + v.w;
#pragma unroll
  for (int m = 1; m < 64; m <<= 1) s += __shfl_xor(s, m);
  const float mean = s * (1.f / 256.f);
  const float dx = v.x - mean, dy = v.y - mean, dz = v.z - mean, dw = v.w - mean;
  float qv = dx * dx + dy * dy + dz * dz + dw * dw;
#pragma unroll
  for (int m = 1; m < 64; m <<= 1) qv += __shfl_xor(qv, m);
  const float rinv = rsqrtf(qv * (1.f / 256.f) + 1e-5f);
  const float4 gg = *(const float4*)(g + lane * 4);
  const float4 bb = *(const float4*)(b + lane * 4);
  u16x4 ov;
  ov[0] = f2bf_bits(dx * rinv * gg.x + bb.x);
  ov[1] = f2bf_bits(dy * rinv * gg.y + bb.y);
  ov[2] = f2bf_bits(dz * rinv * gg.z + bb.z);
  ov[3] = f2bf_bits(dw * rinv * gg.w + bb.w);
  *(u16x4*)(out + (size_t)token * EMB + lane * 4) = ov;
}

// ---------------- GEMM: C[M,N] = A[M,K](bf16) * WT[N,K]^T (bf16), fused epilogues -----
// Tile BM x BN (64 or 128), 4 waves in 2x2, K-step 64.
// MODE 0: qkv scatter -> q[bh][s][d], k[bh][s][d], vT[bh][d][s] (bf16)
// MODE 1/3: + bias + resid(f32) -> f32 out
// MODE 2: + bias + exact GELU -> bf16 out
template <int MODE, int BM, int BN>
__global__ __launch_bounds__(256) void gemm_kernel(
    const unsigned short* __restrict__ A, const unsigned short* __restrict__ WT,
    const float* __restrict__ bias, const float* __restrict__ resid,
    void* __restrict__ out0, void* __restrict__ out1, void* __restrict__ out2,
    int K, int N) {
  constexpr int MF = BM / 32, NF = BN / 32;  // frags per wave (wave tile = BM/2 x BN/2)
  __shared__ __align__(16) short ldsA[BM * 64];
  __shared__ __align__(16) short ldsB[BN * 64];
  const int tid = threadIdx.x;
  const int lane = tid & 63, wid = tid >> 6;
  const int llo = lane & 15, lhi = lane >> 4;
  const int m0 = blockIdx.x * BM;
  const int n0 = blockIdx.y * BN;
  const int wm = (wid >> 1) * (BM / 2), wn = (wid & 1) * (BN / 2);

  f32x4 zero4 = {0.f, 0.f, 0.f, 0.f};
  f32x4 acc[MF][NF];
#pragma unroll
  for (int i = 0; i < MF; ++i)
#pragma unroll
    for (int j = 0; j < NF; ++j) acc[i][j] = zero4;

  const int nkb = K >> 6;
  for (int kb = 0; kb < nkb; ++kb) {
#pragma unroll
    for (int p = 0; p < BM / 32; ++p) {
      int idx = p * 256 + tid;
      int r = idx >> 3, ch = idx & 7;
      bf16x8 va = *(const bf16x8*)(A + (size_t)(m0 + r) * K + kb * 64 + ch * 8);
      *(bf16x8*)&ldsA[r * 64 + ((ch ^ (r & 7)) * 8)] = va;
    }
#pragma unroll
    for (int p = 0; p < BN / 32; ++p) {
      int idx = p * 256 + tid;
      int r = idx >> 3, ch = idx & 7;
      bf16x8 vb = *(const bf16x8*)(WT + (size_t)(n0 + r) * K + kb * 64 + ch * 8);
      *(bf16x8*)&ldsB[r * 64 + ((ch ^ (r & 7)) * 8)] = vb;
    }
    __syncthreads();
#pragma unroll
    for (int ks = 0; ks < 2; ++ks) {
      bf16x8 af[MF], bfr[NF];
#pragma unroll
      for (int mf = 0; mf < MF; ++mf) {
        int r = wm + mf * 16 + llo;
        af[mf] = *(const bf16x8*)&ldsA[r * 64 + (((ks * 4 + lhi) ^ (r & 7)) * 8)];
      }
#pragma unroll
      for (int nf = 0; nf < NF; ++nf) {
        int r = wn + nf * 16 + llo;
        bfr[nf] = *(const bf16x8*)&ldsB[r * 64 + (((ks * 4 + lhi) ^ (r & 7)) * 8)];
      }
#pragma unroll
      for (int mf = 0; mf < MF; ++mf)
#pragma unroll
        for (int nf = 0; nf < NF; ++nf)
          acc[mf][nf] = __builtin_amdgcn_mfma_f32_16x16x32_bf16(af[mf], bfr[nf], acc[mf][nf], 0, 0, 0);
    }
    __syncthreads();
  }

#pragma unroll
  for (int mf = 0; mf < MF; ++mf) {
#pragma unroll
    for (int nf = 0; nf < NF; ++nf) {
      const int n = n0 + wn + nf * 16 + llo;
      const float bv = bias[n];
#pragma unroll
      for (int r = 0; r < 4; ++r) {
        const int m = m0 + wm + mf * 16 + lhi * 4 + r;
        float val = acc[mf][nf][r] + bv;
        if constexpr (MODE == 0) {
          const int part = n >> 8, rem = n & 255, h = rem >> 5, d = rem & 31;
          const int bb = m >> 12, s = m & 4095, bh = bb * 8 + h;
          unsigned short ob = f2bf_bits(val);
          if (part == 0)
            ((unsigned short*)out0)[((size_t)bh * SEQ + s) * HD + d] = ob;
          else if (part == 1)
            ((unsigned short*)out1)[((size_t)bh * SEQ + s) * HD + d] = ob;
          else
            ((unsigned short*)out2)[((size_t)bh * HD + d) * SEQ + s] = ob;
        } else if constexpr (MODE == 2) {
          float gel = 0.5f * val * (1.0f + erff(val * 0.70710678118654752f));
          ((unsigned short*)out0)[(size_t)m * N + n] = f2bf_bits(gel);
        } else {
          ((float*)out0)[(size_t)m * N + n] = val + resid[(size_t)m * N + n];
        }
      }
    }
  }
}

// ---------------- flash attention: 4 waves x 16 q-rows, 64-key tiles ----------------
// 1024 blocks (4/CU, 16 waves/CU). plds is WAVE-PRIVATE -> no block barriers in the
// main loop (avoids the implicit vmcnt(0) drain that would kill K/V reg prefetch).
__global__ __launch_bounds__(256) void attn_kernel(const unsigned short* __restrict__ q,
                                                   const unsigned short* __restrict__ k,
                                                   const unsigned short* __restrict__ vT,
                                                   unsigned short* __restrict__ o) {
  __shared__ __align__(16) short plds[4][16 * 64];
  const int tid = threadIdx.x, lane = tid & 63, wid = tid >> 6;
  const int llo = lane & 15, lhi = lane >> 4;
  const int bh = blockIdx.y, qb = blockIdx.x;
  const int bb = bh >> 3, hh = bh & 7;
  const int q0 = qb * 64 + wid * 16;
  const unsigned short* qp = q + (size_t)bh * SEQ * HD;
  const unsigned short* kp = k + (size_t)bh * SEQ * HD;
  const unsigned short* vp = vT + (size_t)bh * HD * SEQ;

  f32x4 zero4 = {0.f, 0.f, 0.f, 0.f};
  bf16x8 qf = *(const bf16x8*)(qp + (size_t)(q0 + llo) * HD + lhi * 8);

  f32x4 acc[2];
  float mrun[4], lrun[4];
  acc[0] = zero4;
  acc[1] = zero4;
#pragma unroll
  for (int r = 0; r < 4; ++r) { mrun[r] = -1e30f; lrun[r] = 0.f; }

  bf16x8 kf0[4], vf0[4], kf1[4], vf1[4];

  auto load_k = [&](int tt, bf16x8(&kf)[4]) {
#pragma unroll
    for (int tf = 0; tf < 4; ++tf)
      kf[tf] = *(const bf16x8*)(kp + (size_t)(tt * 64 + tf * 16 + llo) * HD + lhi * 8);
  };
  auto load_v = [&](int tt, bf16x8(&vf)[4]) {
#pragma unroll
    for (int df = 0; df < 2; ++df)
#pragma unroll
      for (int ks = 0; ks < 2; ++ks)
        vf[df * 2 + ks] =
            *(const bf16x8*)(vp + (size_t)(df * 16 + llo) * SEQ + tt * 64 + ks * 32 + lhi * 8);
  };

  const float scale = 0.17677669529663687f;

  auto step = [&](int tt, bf16x8(&kf)[4], bf16x8(&vf)[4], bf16x8(&kn)[4], bf16x8(&vn)[4]) {
    int tn = tt + 1;
    if (tn > 63) tn = 63;
    load_k(tn, kn);
    load_v(tn, vn);
    f32x4 sc[4];
#pragma unroll
    for (int tf = 0; tf < 4; ++tf)
      sc[tf] = __builtin_amdgcn_mfma_f32_16x16x32_bf16(qf, kf[tf], zero4, 0, 0, 0);
#pragma unroll
    for (int r = 0; r < 4; ++r) {
      float rm = fmaxf(fmaxf(sc[0][r], sc[1][r]), fmaxf(sc[2][r], sc[3][r]));
      rm = fmaxf(rm, __shfl_xor(rm, 1));
      rm = fmaxf(rm, __shfl_xor(rm, 2));
      rm = fmaxf(rm, __shfl_xor(rm, 4));
      rm = fmaxf(rm, __shfl_xor(rm, 8));
      rm *= scale;
      const float mn = fmaxf(mrun[r], rm);
      const float al = __expf(mrun[r] - mn);
      mrun[r] = mn;
      float rs = 0.f;
#pragma unroll
      for (int tf = 0; tf < 4; ++tf) {
        float p = __expf(__builtin_fmaf(sc[tf][r], scale, -mn));
        sc[tf][r] = p;
        rs += p;
      }
      rs += __shfl_xor(rs, 1);
      rs += __shfl_xor(rs, 2);
      rs += __shfl_xor(rs, 4);
      rs += __shfl_xor(rs, 8);
      lrun[r] = lrun[r] * al + rs;
      acc[0][r] *= al;
      acc[1][r] *= al;
    }
    // P -> LDS (truncating bf16: P in (0,1], rel err <= 2^-8; l-sum stays exact f32)
#pragma unroll
    for (int tf = 0; tf < 4; ++tf)
#pragma unroll
      for (int r = 0; r < 4; ++r) {
        const int row = lhi * 4 + r;
        const int col = tf * 16 + llo;
        const int sch = (col >> 3) ^ (row & 7);
        plds[wid][row * 64 + sch * 8 + (col & 7)] =
            (short)(__builtin_bit_cast(unsigned, sc[tf][r]) >> 16);
      }
    // no __syncthreads(): plds[wid] is wave-private; in-wave LDS ordering suffices
#pragma unroll
    for (int ks = 0; ks < 2; ++ks) {
      const int row = llo;
      const int sch = (ks * 4 + lhi) ^ (row & 7);
      bf16x8 pa = *(const bf16x8*)&plds[wid][row * 64 + sch * 8];
#pragma unroll
      for (int df = 0; df < 2; ++df)
        acc[df] = __builtin_amdgcn_mfma_f32_16x16x32_bf16(pa, vf[df * 2 + ks], acc[df], 0, 0, 0);
    }
  };

  load_k(0, kf0);
  load_v(0, vf0);
  for (int t2 = 0; t2 < 32; ++t2) {
    step(t2 * 2, kf0, vf0, kf1, vf1);
    step(t2 * 2 + 1, kf1, vf1, kf0, vf0);
  }

#pragma unroll
  for (int r = 0; r < 4; ++r) {
    const float rl = 1.0f / lrun[r];
    const int mrow = q0 + lhi * 4 + r;
#pragma unroll
    for (int df = 0; df < 2; ++df) {
      const float val = acc[df][r] * rl;
      o[(size_t)(bb * SEQ + mrow) * EMB + hh * 32 + df * 16 + llo] = f2bf_bits(val);
    }
  }
}

extern "C" void kernel_launch(void* const* d_in, const int* in_sizes, int n_in,
                              void* d_out, int out_size, void* d_ws, size_t ws_size,
                              hipStream_t stream) {
  const float* x = (const float*)d_in[0];
  const float* ln1_g = (const float*)d_in[1];
  const float* ln1_b = (const float*)d_in[2];
  const float* ln2_g = (const float*)d_in[3];
  const float* ln2_b = (const float*)d_in[4];
  const float* w_qkv = (const float*)d_in[5];
  const float* b_qkv = (const float*)d_in[6];
  const float* w_out = (const float*)d_in[7];
  const float* b_out = (const float*)d_in[8];
  const float* w_fc1 = (const float*)d_in[9];
  const float* b_fc1 = (const float*)d_in[10];
  const float* w_fc2 = (const float*)d_in[11];
  const float* b_fc2 = (const float*)d_in[12];
  float* out = (float*)d_out;

  char* ws = (char*)d_ws;
  size_t off = 0;
  auto alloc = [&](size_t bytes) {
    void* p = ws + off;
    off += (bytes + 255) & ~(size_t)255;
    return p;
  };
  unsigned short* wqkvT = (unsigned short*)alloc((size_t)768 * 256 * 2);
  unsigned short* woutT = (unsigned short*)alloc((size_t)256 * 256 * 2);
  unsigned short* wfc1T = (unsigned short*)alloc((size_t)1024 * 256 * 2);
  unsigned short* wfc2T = (unsigned short*)alloc((size_t)256 * 1024 * 2);
  unsigned short* ln1o = (unsigned short*)alloc((size_t)TOKENS * EMB * 2);
  unsigned short* qbuf = (unsigned short*)alloc((size_t)16 * SEQ * HD * 2);
  unsigned short* kbuf = (unsigned short*)alloc((size_t)16 * SEQ * HD * 2);
  unsigned short* vTbuf = (unsigned short*)alloc((size_t)16 * SEQ * HD * 2);
  unsigned short* obuf = (unsigned short*)alloc((size_t)TOKENS * EMB * 2);
  float* x1 = (float*)alloc((size_t)TOKENS * EMB * 4);
  unsigned short* h2 = (unsigned short*)alloc((size_t)TOKENS * EMB * 2);
  unsigned short* ffn1 = (unsigned short*)alloc((size_t)TOKENS * FFN_DIM * 2);

  dim3 blk(256);
  wtrans_all_kernel<<<dim3(3072), blk, 0, stream>>>(w_qkv, w_out, w_fc1, w_fc2,
                                                    wqkvT, woutT, wfc1T, wfc2T);

  ln_kernel<<<dim3(TOKENS / 4), blk, 0, stream>>>(x, ln1_g, ln1_b, ln1o);

  gemm_kernel<0, 128, 64><<<dim3(64, 12), blk, 0, stream>>>(ln1o, wqkvT, b_qkv, nullptr,
                                                            qbuf, kbuf, vTbuf, 256, 768);

  attn_kernel<<<dim3(64, 16), blk, 0, stream>>>(qbuf, kbuf, vTbuf, obuf);

  gemm_kernel<1, 64, 64><<<dim3(128, 4), blk, 0, stream>>>(obuf, woutT, b_out, x,
                                                           x1, nullptr, nullptr, 256, 256);

  ln_kernel<<<dim3(TOKENS / 4), blk, 0, stream>>>(x1, ln2_g, ln2_b, h2);

  gemm_kernel<2, 128, 64><<<dim3(64, 16), blk, 0, stream>>>(h2, wfc1T, b_fc1, nullptr,
                                                            ffn1, nullptr, nullptr, 256, 1024);

  gemm_kernel<3, 64, 64><<<dim3(128, 4), blk, 0, stream>>>(ffn1, wfc2T, b_fc2, x1,
                                                           out, nullptr, nullptr, 1024, 256);
}

// Round 10
// 312.914 us; speedup vs baseline: 1.0719x; 1.0209x over previous
//
#include <hip/hip_runtime.h>
#include <hip/hip_bf16.h>
#include <math.h>

typedef __attribute__((ext_vector_type(8))) short bf16x8;
typedef __attribute__((ext_vector_type(4))) float f32x4;
typedef __attribute__((ext_vector_type(4))) unsigned short u16x4;
typedef __attribute__((ext_vector_type(4))) unsigned int u32x4;

#define TOKENS 8192
#define EMB 256
#define SEQ 4096
#define NH 8
#define HD 32
#define FFN_DIM 1024

// 1/sqrt(32) * log2(e): fold softmax scale + base-2 conversion into Q.
#define QK_PRESCALE 0.25503486f

__device__ __forceinline__ unsigned short f2bf_bits(float f) {
  unsigned u = __builtin_bit_cast(unsigned, f);
  u += 0x7FFFu + ((u >> 16) & 1u);
  return (unsigned short)(u >> 16);
}

// pack two positive f32 into bf16 pair (truncating: P in (0,1], rel err <= 2^-8)
__device__ __forceinline__ unsigned pack_bf(float a, float b) {
  return (__builtin_bit_cast(unsigned, a) >> 16) |
         (__builtin_bit_cast(unsigned, b) & 0xFFFF0000u);
}

// ---------------- all-weights convert + transpose (one launch) ----------------
__global__ __launch_bounds__(256) void wtrans_all_kernel(
    const float* __restrict__ w_qkv, const float* __restrict__ w_out,
    const float* __restrict__ w_fc1, const float* __restrict__ w_fc2,
    unsigned short* __restrict__ t_qkv, unsigned short* __restrict__ t_out,
    unsigned short* __restrict__ t_fc1, unsigned short* __restrict__ t_fc2) {
  int id = blockIdx.x * 256 + threadIdx.x;
  const int S0 = 256 * 768, S1 = S0 + 256 * 256, S2 = S1 + 256 * 1024, S3 = S2 + 1024 * 256;
  if (id < S0) {
    int n = id / 256, kk = id - n * 256;
    t_qkv[id] = f2bf_bits(w_qkv[(size_t)kk * 768 + n]);
  } else if (id < S1) {
    int r = id - S0; int n = r / 256, kk = r - n * 256;
    t_out[r] = f2bf_bits(w_out[(size_t)kk * 256 + n]);
  } else if (id < S2) {
    int r = id - S1; int n = r / 256, kk = r - n * 256;
    t_fc1[r] = f2bf_bits(w_fc1[(size_t)kk * 1024 + n]);
  } else if (id < S3) {
    int r = id - S2; int n = r / 1024, kk = r - n * 1024;
    t_fc2[r] = f2bf_bits(w_fc2[(size_t)kk * 256 + n]);
  }
}

// ---------------- layernorm: fp32 in -> bf16 out (one wave per token) ----------------
__global__ __launch_bounds__(256) void ln_kernel(const float* __restrict__ x,
                                                 const float* __restrict__ g,
                                                 const float* __restrict__ b,
                                                 unsigned short* __restrict__ out) {
  const int tid = threadIdx.x, lane = tid & 63, wid = tid >> 6;
  const int token = blockIdx.x * 4 + wid;
  const float4 v = *(const float4*)(x + (size_t)token * EMB + lane * 4);
  float s = v.x + v.y + v.z + v.w;
#pragma unroll
  for (int m = 1; m < 64; m <<= 1) s += __shfl_xor(s, m);
  const float mean = s * (1.f / 256.f);
  const float dx = v.x - mean, dy = v.y - mean, dz = v.z - mean, dw = v.w - mean;
  float qv = dx * dx + dy * dy + dz * dz + dw * dw;
#pragma unroll
  for (int m = 1; m < 64; m <<= 1) qv += __shfl_xor(qv, m);
  const float rinv = rsqrtf(qv * (1.f / 256.f) + 1e-5f);
  const float4 gg = *(const float4*)(g + lane * 4);
  const float4 bb = *(const float4*)(b + lane * 4);
  u16x4 ov;
  ov[0] = f2bf_bits(dx * rinv * gg.x + bb.x);
  ov[1] = f2bf_bits(dy * rinv * gg.y + bb.y);
  ov[2] = f2bf_bits(dz * rinv * gg.z + bb.z);
  ov[3] = f2bf_bits(dw * rinv * gg.w + bb.w);
  *(u16x4*)(out + (size_t)token * EMB + lane * 4) = ov;
}

// ---------------- GEMM: C[M,N] = A[M,K](bf16) * WT[N,K]^T (bf16), fused epilogues -----
// MODE 0: qkv scatter -> q(prescaled)[bh][s][d], k[bh][s][d], vT[bh][d][s] (bf16)
// MODE 1/3: + bias + resid(f32) -> f32 out ; MODE 2: + bias + exact GELU -> bf16 out
template <int MODE, int BM, int BN>
__global__ __launch_bounds__(256) void gemm_kernel(
    const unsigned short* __restrict__ A, const unsigned short* __restrict__ WT,
    const float* __restrict__ bias, const float* __restrict__ resid,
    void* __restrict__ out0, void* __restrict__ out1, void* __restrict__ out2,
    int K, int N) {
  constexpr int MF = BM / 32, NF = BN / 32;
  __shared__ __align__(16) short ldsA[BM * 64];
  __shared__ __align__(16) short ldsB[BN * 64];
  const int tid = threadIdx.x;
  const int lane = tid & 63, wid = tid >> 6;
  const int llo = lane & 15, lhi = lane >> 4;
  const int m0 = blockIdx.x * BM;
  const int n0 = blockIdx.y * BN;
  const int wm = (wid >> 1) * (BM / 2), wn = (wid & 1) * (BN / 2);

  f32x4 zero4 = {0.f, 0.f, 0.f, 0.f};
  f32x4 acc[MF][NF];
#pragma unroll
  for (int i = 0; i < MF; ++i)
#pragma unroll
    for (int j = 0; j < NF; ++j) acc[i][j] = zero4;

  const int nkb = K >> 6;
  for (int kb = 0; kb < nkb; ++kb) {
#pragma unroll
    for (int p = 0; p < BM / 32; ++p) {
      int idx = p * 256 + tid;
      int r = idx >> 3, ch = idx & 7;
      bf16x8 va = *(const bf16x8*)(A + (size_t)(m0 + r) * K + kb * 64 + ch * 8);
      *(bf16x8*)&ldsA[r * 64 + ((ch ^ (r & 7)) * 8)] = va;
    }
#pragma unroll
    for (int p = 0; p < BN / 32; ++p) {
      int idx = p * 256 + tid;
      int r = idx >> 3, ch = idx & 7;
      bf16x8 vb = *(const bf16x8*)(WT + (size_t)(n0 + r) * K + kb * 64 + ch * 8);
      *(bf16x8*)&ldsB[r * 64 + ((ch ^ (r & 7)) * 8)] = vb;
    }
    __syncthreads();
#pragma unroll
    for (int ks = 0; ks < 2; ++ks) {
      bf16x8 af[MF], bfr[NF];
#pragma unroll
      for (int mf = 0; mf < MF; ++mf) {
        int r = wm + mf * 16 + llo;
        af[mf] = *(const bf16x8*)&ldsA[r * 64 + (((ks * 4 + lhi) ^ (r & 7)) * 8)];
      }
#pragma unroll
      for (int nf = 0; nf < NF; ++nf) {
        int r = wn + nf * 16 + llo;
        bfr[nf] = *(const bf16x8*)&ldsB[r * 64 + (((ks * 4 + lhi) ^ (r & 7)) * 8)];
      }
#pragma unroll
      for (int mf = 0; mf < MF; ++mf)
#pragma unroll
        for (int nf = 0; nf < NF; ++nf)
          acc[mf][nf] = __builtin_amdgcn_mfma_f32_16x16x32_bf16(af[mf], bfr[nf], acc[mf][nf], 0, 0, 0);
    }
    __syncthreads();
  }

#pragma unroll
  for (int mf = 0; mf < MF; ++mf) {
#pragma unroll
    for (int nf = 0; nf < NF; ++nf) {
      const int n = n0 + wn + nf * 16 + llo;
      const float bv = bias[n];
#pragma unroll
      for (int r = 0; r < 4; ++r) {
        const int m = m0 + wm + mf * 16 + lhi * 4 + r;
        float val = acc[mf][nf][r] + bv;
        if constexpr (MODE == 0) {
          const int part = n >> 8, rem = n & 255, h = rem >> 5, d = rem & 31;
          const int bb = m >> 12, s = m & 4095, bh = bb * 8 + h;
          if (part == 0) {
            ((unsigned short*)out0)[((size_t)bh * SEQ + s) * HD + d] =
                f2bf_bits(val * QK_PRESCALE);
          } else if (part == 1) {
            ((unsigned short*)out1)[((size_t)bh * SEQ + s) * HD + d] = f2bf_bits(val);
          } else {
            ((unsigned short*)out2)[((size_t)bh * HD + d) * SEQ + s] = f2bf_bits(val);
          }
        } else if constexpr (MODE == 2) {
          float gel = 0.5f * val * (1.0f + erff(val * 0.70710678118654752f));
          ((unsigned short*)out0)[(size_t)m * N + n] = f2bf_bits(gel);
        } else {
          ((float*)out0)[(size_t)m * N + n] = val + resid[(size_t)m * N + n];
        }
      }
    }
  }
}

// ---------------- flash attention: swapped-QK, lane-local softmax, zero LDS ---------
// Each wave: 16 q-rows, 64-key steps. mfma(K,Q) puts a full score row in one lane
// (qrow = lane&15): row reductions are 15 in-lane ops + 2 shfl (was 32 shfl).
// P redistribution for PV via 16 ds_bpermute + select (no LDS round-trip).
__global__ __launch_bounds__(256) void attn_kernel(const unsigned short* __restrict__ q,
                                                   const unsigned short* __restrict__ k,
                                                   const unsigned short* __restrict__ vT,
                                                   unsigned short* __restrict__ o) {
  const int tid = threadIdx.x, lane = tid & 63, wid = tid >> 6;
  const int llo = lane & 15, lhi = lane >> 4;
  const int bh = blockIdx.y, qb = blockIdx.x;
  const int bb = bh >> 3, hh = bh & 7;
  const int q0 = qb * 64 + wid * 16;
  const unsigned short* qp = q + (size_t)bh * SEQ * HD;
  const unsigned short* kp = k + (size_t)bh * SEQ * HD;
  const unsigned short* vp = vT + (size_t)bh * HD * SEQ;

  f32x4 zero4 = {0.f, 0.f, 0.f, 0.f};
  // Q as B-operand: col = llo = qrow, k = lhi*8.. (same bytes as A-layout load)
  bf16x8 qf = *(const bf16x8*)(qp + (size_t)(q0 + llo) * HD + lhi * 8);

  f32x4 acc[2];
  acc[0] = zero4;
  acc[1] = zero4;
  float mrun = -3.0e38f, lrun = 0.f;

  // loop-invariant bpermute byte-addresses
  const int addr0 = 4 * (llo + 32 * (lhi & 1));  // src group 2*(lhi&1), words c=0,1
  const int addr1 = addr0 + 64;                  // src group 2*(lhi&1)+1, words c=2,3
  const int addrR = 4 * (lhi * 4);               // row-broadcast base (rows lhi*4+r)
  const bool hiSel = (lhi >= 2);

  bf16x8 kf0[4], kf1[4], vf[4];

  auto load_k = [&](int tt, bf16x8(&kf)[4]) {
#pragma unroll
    for (int tf = 0; tf < 4; ++tf)
      kf[tf] = *(const bf16x8*)(kp + (size_t)(tt * 64 + tf * 16 + llo) * HD + lhi * 8);
  };
  auto load_v = [&](int tt) {
#pragma unroll
    for (int df = 0; df < 2; ++df)
#pragma unroll
      for (int ks = 0; ks < 2; ++ks)
        vf[df * 2 + ks] =
            *(const bf16x8*)(vp + (size_t)(df * 16 + llo) * SEQ + tt * 64 + ks * 32 + lhi * 8);
  };

  auto step = [&](int tt, bf16x8(&kf)[4], bf16x8(&kn)[4]) {
    load_v(tt);  // V for THIS step: consumed after softmax (~200cyc cover)
    f32x4 sc[4];
#pragma unroll
    for (int tf = 0; tf < 4; ++tf)
      sc[tf] = __builtin_amdgcn_mfma_f32_16x16x32_bf16(kf[tf], qf, zero4, 0, 0, 0);
    int tn = tt + 1;
    if (tn > 63) tn = 63;
    load_k(tn, kn);  // K prefetch for next step

    // in-lane row max over 16 scores (row = llo), then cross-group (2 shfl)
    float m16 = fmaxf(fmaxf(sc[0][0], sc[0][1]), fmaxf(sc[0][2], sc[0][3]));
#pragma unroll
    for (int tf = 1; tf < 4; ++tf)
      m16 = fmaxf(m16, fmaxf(fmaxf(sc[tf][0], sc[tf][1]), fmaxf(sc[tf][2], sc[tf][3])));
    m16 = fmaxf(m16, __shfl_xor(m16, 16));
    m16 = fmaxf(m16, __shfl_xor(m16, 32));
    const float mn = fmaxf(mrun, m16);
    const float nm = -mn;
    const float al = exp2f(mrun - mn);
    mrun = mn;

    float rs = 0.f;
#pragma unroll
    for (int tf = 0; tf < 4; ++tf)
#pragma unroll
      for (int r = 0; r < 4; ++r) {
        float p = exp2f(sc[tf][r] + nm);
        sc[tf][r] = p;
        rs += p;
      }
    rs += __shfl_xor(rs, 16);
    rs += __shfl_xor(rs, 32);
    lrun = lrun * al + rs;

    // broadcast al to acc rows (acc row = lhi*4+r, al lives at lane llo=row)
#pragma unroll
    for (int r = 0; r < 4; ++r) {
      float alr = __builtin_bit_cast(
          float, __builtin_amdgcn_ds_bpermute(addrR + 4 * r,
                                              __builtin_bit_cast(int, al)));
      acc[0][r] *= alr;
      acc[1][r] *= alr;
    }

    // pack P to bf16 pairs: w[tf][wi] covers keys tf*16 + lhi*4 + 2wi + {0,1}
    unsigned w[4][2];
#pragma unroll
    for (int tf = 0; tf < 4; ++tf) {
      w[tf][0] = pack_bf(sc[tf][0], sc[tf][1]);
      w[tf][1] = pack_bf(sc[tf][2], sc[tf][3]);
    }

    // exchange to A-fragment layout + PV
#pragma unroll
    for (int ks = 0; ks < 2; ++ks) {
      int aL0 = __builtin_amdgcn_ds_bpermute(addr0, (int)w[2 * ks][0]);
      int bL0 = __builtin_amdgcn_ds_bpermute(addr0, (int)w[2 * ks + 1][0]);
      int aL1 = __builtin_amdgcn_ds_bpermute(addr0, (int)w[2 * ks][1]);
      int bL1 = __builtin_amdgcn_ds_bpermute(addr0, (int)w[2 * ks + 1][1]);
      int aH0 = __builtin_amdgcn_ds_bpermute(addr1, (int)w[2 * ks][0]);
      int bH0 = __builtin_amdgcn_ds_bpermute(addr1, (int)w[2 * ks + 1][0]);
      int aH1 = __builtin_amdgcn_ds_bpermute(addr1, (int)w[2 * ks][1]);
      int bH1 = __builtin_amdgcn_ds_bpermute(addr1, (int)w[2 * ks + 1][1]);
      u32x4 c;
      c[0] = (unsigned)(hiSel ? bL0 : aL0);
      c[1] = (unsigned)(hiSel ? bL1 : aL1);
      c[2] = (unsigned)(hiSel ? bH0 : aH0);
      c[3] = (unsigned)(hiSel ? bH1 : aH1);
      bf16x8 pa = __builtin_bit_cast(bf16x8, c);
#pragma unroll
      for (int df = 0; df < 2; ++df)
        acc[df] = __builtin_amdgcn_mfma_f32_16x16x32_bf16(pa, vf[df * 2 + ks], acc[df], 0, 0, 0);
    }
  };

  load_k(0, kf0);
  for (int t2 = 0; t2 < 32; ++t2) {
    step(t2 * 2, kf0, kf1);
    step(t2 * 2 + 1, kf1, kf0);
  }

  const float rl = 1.0f / lrun;
#pragma unroll
  for (int r = 0; r < 4; ++r) {
    float rlr = __builtin_bit_cast(
        float, __builtin_amdgcn_ds_bpermute(addrR + 4 * r,
                                            __builtin_bit_cast(int, rl)));
    const int mrow = q0 + lhi * 4 + r;
#pragma unroll
    for (int df = 0; df < 2; ++df) {
      const float val = acc[df][r] * rlr;
      o[(size_t)(bb * SEQ + mrow) * EMB + hh * 32 + df * 16 + llo] = f2bf_bits(val);
    }
  }
}

extern "C" void kernel_launch(void* const* d_in, const int* in_sizes, int n_in,
                              void* d_out, int out_size, void* d_ws, size_t ws_size,
                              hipStream_t stream) {
  const float* x = (const float*)d_in[0];
  const float* ln1_g = (const float*)d_in[1];
  const float* ln1_b = (const float*)d_in[2];
  const float* ln2_g = (const float*)d_in[3];
  const float* ln2_b = (const float*)d_in[4];
  const float* w_qkv = (const float*)d_in[5];
  const float* b_qkv = (const float*)d_in[6];
  const float* w_out = (const float*)d_in[7];
  const float* b_out = (const float*)d_in[8];
  const float* w_fc1 = (const float*)d_in[9];
  const float* b_fc1 = (const float*)d_in[10];
  const float* w_fc2 = (const float*)d_in[11];
  const float* b_fc2 = (const float*)d_in[12];
  float* out = (float*)d_out;

  char* ws = (char*)d_ws;
  size_t off = 0;
  auto alloc = [&](size_t bytes) {
    void* p = ws + off;
    off += (bytes + 255) & ~(size_t)255;
    return p;
  };
  unsigned short* wqkvT = (unsigned short*)alloc((size_t)768 * 256 * 2);
  unsigned short* woutT = (unsigned short*)alloc((size_t)256 * 256 * 2);
  unsigned short* wfc1T = (unsigned short*)alloc((size_t)1024 * 256 * 2);
  unsigned short* wfc2T = (unsigned short*)alloc((size_t)256 * 1024 * 2);
  unsigned short* ln1o = (unsigned short*)alloc((size_t)TOKENS * EMB * 2);
  unsigned short* qbuf = (unsigned short*)alloc((size_t)16 * SEQ * HD * 2);
  unsigned short* kbuf = (unsigned short*)alloc((size_t)16 * SEQ * HD * 2);
  unsigned short* vTbuf = (unsigned short*)alloc((size_t)16 * SEQ * HD * 2);
  unsigned short* obuf = (unsigned short*)alloc((size_t)TOKENS * EMB * 2);
  float* x1 = (float*)alloc((size_t)TOKENS * EMB * 4);
  unsigned short* h2 = (unsigned short*)alloc((size_t)TOKENS * EMB * 2);
  unsigned short* ffn1 = (unsigned short*)alloc((size_t)TOKENS * FFN_DIM * 2);

  dim3 blk(256);
  wtrans_all_kernel<<<dim3(3072), blk, 0, stream>>>(w_qkv, w_out, w_fc1, w_fc2,
                                                    wqkvT, woutT, wfc1T, wfc2T);

  ln_kernel<<<dim3(TOKENS / 4), blk, 0, stream>>>(x, ln1_g, ln1_b, ln1o);

  gemm_kernel<0, 128, 64><<<dim3(64, 12), blk, 0, stream>>>(ln1o, wqkvT, b_qkv, nullptr,
                                                            qbuf, kbuf, vTbuf, 256, 768);

  attn_kernel<<<dim3(64, 16), blk, 0, stream>>>(qbuf, kbuf, vTbuf, obuf);

  gemm_kernel<1, 64, 64><<<dim3(128, 4), blk, 0, stream>>>(obuf, woutT, b_out, x,
                                                           x1, nullptr, nullptr, 256, 256);

  ln_kernel<<<dim3(TOKENS / 4), blk, 0, stream>>>(x1, ln2_g, ln2_b, h2);

  gemm_kernel<2, 128, 64><<<dim3(64, 16), blk, 0, stream>>>(h2, wfc1T, b_fc1, nullptr,
                                                            ffn1, nullptr, nullptr, 256, 1024);

  gemm_kernel<3, 64, 64><<<dim3(128, 4), blk, 0, stream>>>(ffn1, wfc2T, b_fc2, x1,
                                                           out, nullptr, nullptr, 1024, 256);
}